// Round 13
// baseline (630.836 us; speedup 1.0000x reference)
//
#include <hip/hip_runtime.h>

#define NN 100000
#define NE 1600000
#define DF 32
#define DEPTH 10
#define LSTRIDE ((DEPTH + 1) * DF) /* 352 floats per node in d_out */
#define SCAN_BLOCKS 256
#define SCAN_T 256
#define PAD 8
#define PADM (~(PAD - 1))

// zero cnt only (0.4MB)
__global__ void zcnt_k(int* __restrict__ cnt, int n4) {
    int i = blockIdx.x * blockDim.x + threadIdx.x;
    if (i < n4) ((int4*)cnt)[i] = make_int4(0, 0, 0, 0);
}

// histogram + per-edge rank within its row (atomic result was free)
__global__ void hist_k(const int* __restrict__ row, int* __restrict__ cnt,
                       int* __restrict__ prank, int e) {
    int i = blockIdx.x * blockDim.x + threadIdx.x;
    int stride = gridDim.x * blockDim.x;
    for (; i < e; i += stride) {
        int r = __builtin_nontemporal_load(&row[i]);
        prank[i] = atomicAdd(&cnt[r], 1);
    }
}

// --- multi-block scan over PADDED counts ((cnt+PAD-1)&PADM) ---
__global__ void scan_partial_k(const int* __restrict__ cnt, int* __restrict__ bsum,
                               int n, int chunk) {
    __shared__ int red[SCAN_T];
    int b = blockIdx.x, t = threadIdx.x;
    int beg = b * chunk, end = min(n, beg + chunk);
    int s = 0;
    for (int i = beg + t; i < end; i += SCAN_T) s += (cnt[i] + PAD - 1) & PADM;
    red[t] = s;
    __syncthreads();
    for (int off = SCAN_T / 2; off; off >>= 1) {
        if (t < off) red[t] += red[t + off];
        __syncthreads();
    }
    if (t == 0) bsum[b] = red[0];
}

__global__ void scan_bsum_k(const int* __restrict__ bsum, int* __restrict__ boff) {
    __shared__ int s[SCAN_BLOCKS];
    int t = threadIdx.x;
    s[t] = bsum[t];
    __syncthreads();
    for (int off = 1; off < SCAN_BLOCKS; off <<= 1) {
        int v = (t >= off) ? s[t - off] : 0;
        __syncthreads();
        s[t] += v;
        __syncthreads();
    }
    boff[t] = (t == 0) ? 0 : s[t - 1];
}

// emit padded-exclusive-prefix rowptr; also compute dinv from real cnt (fused).
__global__ void scan_emit_k(const int* __restrict__ cnt, const int* __restrict__ boff,
                            int* __restrict__ rowptr, float* __restrict__ dinv,
                            int n, int chunk) {
    __shared__ int tile[SCAN_T];
    int b = blockIdx.x, t = threadIdx.x;
    int beg = b * chunk, end = min(n, beg + chunk);
    int run = boff[b];
    for (int base = beg; base < end; base += SCAN_T) {
        int i = base + t;
        int creal = (i < end) ? cnt[i] : 0;
        int c = (creal + PAD - 1) & PADM;
        tile[t] = c;
        __syncthreads();
        for (int off = 1; off < SCAN_T; off <<= 1) {
            int v = (t >= off) ? tile[t - off] : 0;
            __syncthreads();
            tile[t] += v;
            __syncthreads();
        }
        if (i < end) {
            rowptr[i] = run + tile[t] - c; // exclusive prefix of padded counts
            float d = (creal == 0) ? 1.0f : (float)creal;
            dinv[i] = rsqrtf(d);
        }
        run += tile[SCAN_T - 1];
        __syncthreads();
    }
    if (b == gridDim.x - 1 && t == 0) rowptr[n] = run;
}

// zero only the pad slots: [rowptr[r]+cnt[r], rowptr[r+1])
__global__ void pad_k(const int* __restrict__ rowptr, const int* __restrict__ cnt,
                      unsigned long long* __restrict__ cpack, int n) {
    int r = blockIdx.x * blockDim.x + threadIdx.x;
    if (r < n) {
        int p = rowptr[r] + cnt[r];
        int end = rowptr[r + 1];
        for (; p < end; ++p) cpack[p] = 0ull;
    }
}

// atomic-free scatter: pos = rowptr[row] + prank
__global__ void scatter_k(const int* __restrict__ row, const int* __restrict__ col,
                          const float* __restrict__ ea, const float* __restrict__ dinv,
                          const int* __restrict__ rowptr, const int* __restrict__ prank,
                          unsigned long long* __restrict__ cpack, int e) {
    int i = blockIdx.x * blockDim.x + threadIdx.x;
    int stride = gridDim.x * blockDim.x;
    for (; i < e; i += stride) {
        int r = __builtin_nontemporal_load(&row[i]);
        int c = __builtin_nontemporal_load(&col[i]);
        float a = __builtin_nontemporal_load(&ea[i]);
        int pr = __builtin_nontemporal_load(&prank[i]);
        float v = dinv[r] * a * dinv[c];
        int pos = rowptr[r] + pr;
        cpack[pos] = ((unsigned long long)(unsigned)__float_as_int(v) << 32) | (unsigned)c;
    }
}

// out[node][0][:] = x[node][:]  (float4 vectorized)
__global__ void copy_k(const float* __restrict__ x, float* __restrict__ out, int n) {
    int t = blockIdx.x * blockDim.x + threadIdx.x; // n*8 float4s
    if (t < n * 8) {
        int node = t >> 3, q = t & 7;
        ((float4*)out)[(size_t)node * (LSTRIDE / 4) + q] = ((const float4*)x)[t];
    }
}

// ONE 64-lane wave per row. lane = (edge-slot eg = lane>>3, feature-quad fq = lane&7).
// One dwordx4 gather instruction fetches 8 edges x 16B (8x fewer VMEM instrs than
// the 32-lane-scalar form); one 8B cpack load serves 8 edges. End-of-row butterfly
// reduce over eg (3 rounds x 4 floats), then lanes eg==0 store a 128B float4 row.
__global__ __launch_bounds__(256) void spmm_k(const int* __restrict__ rowptr,
                                              const unsigned long long* __restrict__ cpack,
                                              const float* __restrict__ pe,
                                              float* __restrict__ out, int n, int layer) {
    int lane = threadIdx.x & 63;
    int gid = blockIdx.x * 4 + (threadIdx.x >> 6);
    if (gid >= n) return;
    int eg = lane >> 3, fq = lane & 7;
    float alpha = tanhf(pe[layer]); // BASE_ALPHA = 1
    const float* __restrict__ hsrc = out + (size_t)layer * DF + fq * 4;
    int beg = rowptr[gid], end = rowptr[gid + 1]; // multiple of 8 apart
    float4 acc = make_float4(0.f, 0.f, 0.f, 0.f);
    for (int base = beg; base < end; base += 8) {
        unsigned long long p = __builtin_nontemporal_load(&cpack[base + eg]);
        unsigned col = (unsigned)(p & 0xFFFFFFFFu);
        float val = __uint_as_float((unsigned)(p >> 32));
        const float4 h4 = *(const float4*)(hsrc + col * (unsigned)LSTRIDE);
        acc.x = fmaf(val, h4.x, acc.x);
        acc.y = fmaf(val, h4.y, acc.y);
        acc.z = fmaf(val, h4.z, acc.z);
        acc.w = fmaf(val, h4.w, acc.w);
    }
#pragma unroll
    for (int s = 8; s < 64; s <<= 1) {
        acc.x += __shfl_xor(acc.x, s);
        acc.y += __shfl_xor(acc.y, s);
        acc.z += __shfl_xor(acc.z, s);
        acc.w += __shfl_xor(acc.w, s);
    }
    if (eg == 0) {
        float4 r = make_float4(alpha * acc.x, alpha * acc.y, alpha * acc.z, alpha * acc.w);
        *(float4*)&out[(size_t)gid * LSTRIDE + (layer + 1) * DF + fq * 4] = r;
    }
}

extern "C" void kernel_launch(void* const* d_in, const int* in_sizes, int n_in,
                              void* d_out, int out_size, void* d_ws, size_t ws_size,
                              hipStream_t stream) {
    const float* x  = (const float*)d_in[0];
    const int*   ei = (const int*)d_in[1];
    const float* ea = (const float*)d_in[2];
    const float* pe = (const float*)d_in[3];
    float* out = (float*)d_out;

    const int n = in_sizes[0] / DF;   // 100000
    const int e = in_sizes[2];        // 1600000
    const int* row = ei;
    const int* col = ei + e;

    // workspace layout
    int*   cnt    = (int*)d_ws;               // n  (16B-aligned: ws base)
    int*   rowptr = cnt + n;                  // n+1
    float* dinv   = (float*)(rowptr + n + 1); // n
    int*   bsum   = (int*)(dinv + n);         // SCAN_BLOCKS
    int*   boff   = bsum + SCAN_BLOCKS;       // SCAN_BLOCKS
    int*   prank  = boff + SCAN_BLOCKS;       // e
    size_t off = ((size_t)(prank + e) - (size_t)d_ws + 15) & ~(size_t)15;
    unsigned long long* cpack = (unsigned long long*)((char*)d_ws + off); // e + (PAD-1)n

    const int n4_cnt = (n + 3) / 4;
    const int chunk = (n + SCAN_BLOCKS - 1) / SCAN_BLOCKS;

    zcnt_k<<<(n4_cnt + 255) / 256, 256, 0, stream>>>(cnt, n4_cnt);
    hist_k<<<2048, 256, 0, stream>>>(row, cnt, prank, e);
    scan_partial_k<<<SCAN_BLOCKS, SCAN_T, 0, stream>>>(cnt, bsum, n, chunk);
    scan_bsum_k<<<1, SCAN_BLOCKS, 0, stream>>>(bsum, boff);
    scan_emit_k<<<SCAN_BLOCKS, SCAN_T, 0, stream>>>(cnt, boff, rowptr, dinv, n, chunk);
    pad_k<<<(n + 255) / 256, 256, 0, stream>>>(rowptr, cnt, cpack, n);
    scatter_k<<<2048, 256, 0, stream>>>(row, col, ea, dinv, rowptr, prank, cpack, e);
    copy_k<<<(n * 8 + 255) / 256, 256, 0, stream>>>(x, out, n);

    for (int L = 0; L < DEPTH; ++L) {
        spmm_k<<<(n + 3) / 4, 256, 0, stream>>>(rowptr, cpack, pe, out, n, L);
    }
}

// Round 14
// 566.021 us; speedup vs baseline: 1.1145x; 1.1145x over previous
//
#include <hip/hip_runtime.h>

#define NN 100000
#define NE 1600000
#define DF 32
#define DEPTH 10
#define LSTRIDE ((DEPTH + 1) * DF) /* 352 floats per node in d_out */
#define SCAN_BLOCKS 256
#define SCAN_T 256
#define PAD 8
#define PADM (~(PAD - 1))

// zero cnt only (0.4MB)
__global__ void zcnt_k(int* __restrict__ cnt, int n4) {
    int i = blockIdx.x * blockDim.x + threadIdx.x;
    if (i < n4) ((int4*)cnt)[i] = make_int4(0, 0, 0, 0);
}

// histogram + per-edge rank within its row (atomic result was free)
__global__ void hist_k(const int* __restrict__ row, int* __restrict__ cnt,
                       int* __restrict__ prank, int e) {
    int i = blockIdx.x * blockDim.x + threadIdx.x;
    int stride = gridDim.x * blockDim.x;
    for (; i < e; i += stride) {
        int r = __builtin_nontemporal_load(&row[i]);
        prank[i] = atomicAdd(&cnt[r], 1);
    }
}

// --- multi-block scan over PADDED counts ((cnt+PAD-1)&PADM) ---
__global__ void scan_partial_k(const int* __restrict__ cnt, int* __restrict__ bsum,
                               int n, int chunk) {
    __shared__ int red[SCAN_T];
    int b = blockIdx.x, t = threadIdx.x;
    int beg = b * chunk, end = min(n, beg + chunk);
    int s = 0;
    for (int i = beg + t; i < end; i += SCAN_T) s += (cnt[i] + PAD - 1) & PADM;
    red[t] = s;
    __syncthreads();
    for (int off = SCAN_T / 2; off; off >>= 1) {
        if (t < off) red[t] += red[t + off];
        __syncthreads();
    }
    if (t == 0) bsum[b] = red[0];
}

__global__ void scan_bsum_k(const int* __restrict__ bsum, int* __restrict__ boff) {
    __shared__ int s[SCAN_BLOCKS];
    int t = threadIdx.x;
    s[t] = bsum[t];
    __syncthreads();
    for (int off = 1; off < SCAN_BLOCKS; off <<= 1) {
        int v = (t >= off) ? s[t - off] : 0;
        __syncthreads();
        s[t] += v;
        __syncthreads();
    }
    boff[t] = (t == 0) ? 0 : s[t - 1];
}

// emit padded-exclusive-prefix rowptr; also compute dinv from real cnt (fused).
__global__ void scan_emit_k(const int* __restrict__ cnt, const int* __restrict__ boff,
                            int* __restrict__ rowptr, float* __restrict__ dinv,
                            int n, int chunk) {
    __shared__ int tile[SCAN_T];
    int b = blockIdx.x, t = threadIdx.x;
    int beg = b * chunk, end = min(n, beg + chunk);
    int run = boff[b];
    for (int base = beg; base < end; base += SCAN_T) {
        int i = base + t;
        int creal = (i < end) ? cnt[i] : 0;
        int c = (creal + PAD - 1) & PADM;
        tile[t] = c;
        __syncthreads();
        for (int off = 1; off < SCAN_T; off <<= 1) {
            int v = (t >= off) ? tile[t - off] : 0;
            __syncthreads();
            tile[t] += v;
            __syncthreads();
        }
        if (i < end) {
            rowptr[i] = run + tile[t] - c; // exclusive prefix of padded counts
            float d = (creal == 0) ? 1.0f : (float)creal;
            dinv[i] = rsqrtf(d);
        }
        run += tile[SCAN_T - 1];
        __syncthreads();
    }
    if (b == gridDim.x - 1 && t == 0) rowptr[n] = run;
}

// zero only the pad slots: [rowptr[r]+cnt[r], rowptr[r+1])
__global__ void pad_k(const int* __restrict__ rowptr, const int* __restrict__ cnt,
                      unsigned long long* __restrict__ cpack, int n) {
    int r = blockIdx.x * blockDim.x + threadIdx.x;
    if (r < n) {
        int p = rowptr[r] + cnt[r];
        int end = rowptr[r + 1];
        for (; p < end; ++p) cpack[p] = 0ull;
    }
}

// atomic-free scatter: pos = rowptr[row] + prank
__global__ void scatter_k(const int* __restrict__ row, const int* __restrict__ col,
                          const float* __restrict__ ea, const float* __restrict__ dinv,
                          const int* __restrict__ rowptr, const int* __restrict__ prank,
                          unsigned long long* __restrict__ cpack, int e) {
    int i = blockIdx.x * blockDim.x + threadIdx.x;
    int stride = gridDim.x * blockDim.x;
    for (; i < e; i += stride) {
        int r = __builtin_nontemporal_load(&row[i]);
        int c = __builtin_nontemporal_load(&col[i]);
        float a = __builtin_nontemporal_load(&ea[i]);
        int pr = __builtin_nontemporal_load(&prank[i]);
        float v = dinv[r] * a * dinv[c];
        int pos = rowptr[r] + pr;
        cpack[pos] = ((unsigned long long)(unsigned)__float_as_int(v) << 32) | (unsigned)c;
    }
}

// out[node][0][:] = x[node][:]  (float4 vectorized)
__global__ void copy_k(const float* __restrict__ x, float* __restrict__ out, int n) {
    int t = blockIdx.x * blockDim.x + threadIdx.x; // n*8 float4s
    if (t < n * 8) {
        int node = t >> 3, q = t & 7;
        ((float4*)out)[(size_t)node * (LSTRIDE / 4) + q] = ((const float4*)x)[t];
    }
}

// TWO rows per 32-lane group, interleaved unroll-8: 16 independent gathers in
// flight while both rows active (deg~16 => usually 2 common batches). No masks,
// no extra traffic vs R12; uniform per-group tails.
__global__ __launch_bounds__(256) void spmm_k(const int* __restrict__ rowptr,
                                              const unsigned long long* __restrict__ cpack,
                                              const float* __restrict__ pe,
                                              float* __restrict__ out, int n, int layer) {
    int grp = blockIdx.x * 8 + (threadIdx.x >> 5);
    int lane = threadIdx.x & 31;
    int rA = grp * 2, rB = rA + 1;
    if (rA >= n) return;
    float alpha = tanhf(pe[layer]); // BASE_ALPHA = 1
    const float* __restrict__ hsrc = out + (size_t)layer * DF + lane;
    float accA = 0.f, accB = 0.f;
    int baseA = rowptr[rA], endA = rowptr[rA + 1];
    bool hasB = (rB < n);
    int baseB = hasB ? rowptr[rB] : 0;
    int endB  = hasB ? rowptr[rB + 1] : 0;

    // interleaved common part: 16 gathers in flight
    while (baseA < endA && baseB < endB) {
        unsigned long long pA[8], pB[8];
#pragma unroll
        for (int u = 0; u < 8; ++u) pA[u] = __builtin_nontemporal_load(&cpack[baseA + u]);
#pragma unroll
        for (int u = 0; u < 8; ++u) pB[u] = __builtin_nontemporal_load(&cpack[baseB + u]);
        float hA[8], hB[8];
#pragma unroll
        for (int u = 0; u < 8; ++u)
            hA[u] = hsrc[(unsigned)(pA[u] & 0xFFFFFFFFu) * (unsigned)LSTRIDE];
#pragma unroll
        for (int u = 0; u < 8; ++u)
            hB[u] = hsrc[(unsigned)(pB[u] & 0xFFFFFFFFu) * (unsigned)LSTRIDE];
#pragma unroll
        for (int u = 0; u < 8; ++u)
            accA = fmaf(__uint_as_float((unsigned)(pA[u] >> 32)), hA[u], accA);
#pragma unroll
        for (int u = 0; u < 8; ++u)
            accB = fmaf(__uint_as_float((unsigned)(pB[u] >> 32)), hB[u], accB);
        baseA += 8;
        baseB += 8;
    }
    // tails (group-uniform branches)
    for (; baseA < endA; baseA += 8) {
        unsigned long long p[8];
#pragma unroll
        for (int u = 0; u < 8; ++u) p[u] = __builtin_nontemporal_load(&cpack[baseA + u]);
        float h[8];
#pragma unroll
        for (int u = 0; u < 8; ++u)
            h[u] = hsrc[(unsigned)(p[u] & 0xFFFFFFFFu) * (unsigned)LSTRIDE];
#pragma unroll
        for (int u = 0; u < 8; ++u)
            accA = fmaf(__uint_as_float((unsigned)(p[u] >> 32)), h[u], accA);
    }
    for (; baseB < endB; baseB += 8) {
        unsigned long long p[8];
#pragma unroll
        for (int u = 0; u < 8; ++u) p[u] = __builtin_nontemporal_load(&cpack[baseB + u]);
        float h[8];
#pragma unroll
        for (int u = 0; u < 8; ++u)
            h[u] = hsrc[(unsigned)(p[u] & 0xFFFFFFFFu) * (unsigned)LSTRIDE];
#pragma unroll
        for (int u = 0; u < 8; ++u)
            accB = fmaf(__uint_as_float((unsigned)(p[u] >> 32)), h[u], accB);
    }

    out[(size_t)rA * LSTRIDE + (layer + 1) * DF + lane] = alpha * accA;
    if (hasB)
        out[(size_t)rB * LSTRIDE + (layer + 1) * DF + lane] = alpha * accB;
}

extern "C" void kernel_launch(void* const* d_in, const int* in_sizes, int n_in,
                              void* d_out, int out_size, void* d_ws, size_t ws_size,
                              hipStream_t stream) {
    const float* x  = (const float*)d_in[0];
    const int*   ei = (const int*)d_in[1];
    const float* ea = (const float*)d_in[2];
    const float* pe = (const float*)d_in[3];
    float* out = (float*)d_out;

    const int n = in_sizes[0] / DF;   // 100000
    const int e = in_sizes[2];        // 1600000
    const int* row = ei;
    const int* col = ei + e;

    // workspace layout
    int*   cnt    = (int*)d_ws;               // n  (16B-aligned: ws base)
    int*   rowptr = cnt + n;                  // n+1
    float* dinv   = (float*)(rowptr + n + 1); // n
    int*   bsum   = (int*)(dinv + n);         // SCAN_BLOCKS
    int*   boff   = bsum + SCAN_BLOCKS;       // SCAN_BLOCKS
    int*   prank  = boff + SCAN_BLOCKS;       // e
    size_t off = ((size_t)(prank + e) - (size_t)d_ws + 15) & ~(size_t)15;
    unsigned long long* cpack = (unsigned long long*)((char*)d_ws + off); // e + (PAD-1)n

    const int n4_cnt = (n + 3) / 4;
    const int chunk = (n + SCAN_BLOCKS - 1) / SCAN_BLOCKS;

    zcnt_k<<<(n4_cnt + 255) / 256, 256, 0, stream>>>(cnt, n4_cnt);
    hist_k<<<2048, 256, 0, stream>>>(row, cnt, prank, e);
    scan_partial_k<<<SCAN_BLOCKS, SCAN_T, 0, stream>>>(cnt, bsum, n, chunk);
    scan_bsum_k<<<1, SCAN_BLOCKS, 0, stream>>>(bsum, boff);
    scan_emit_k<<<SCAN_BLOCKS, SCAN_T, 0, stream>>>(cnt, boff, rowptr, dinv, n, chunk);
    pad_k<<<(n + 255) / 256, 256, 0, stream>>>(rowptr, cnt, cpack, n);
    scatter_k<<<2048, 256, 0, stream>>>(row, col, ea, dinv, rowptr, prank, cpack, e);
    copy_k<<<(n * 8 + 255) / 256, 256, 0, stream>>>(x, out, n);

    const int ngrp = (n + 1) / 2;
    for (int L = 0; L < DEPTH; ++L) {
        spmm_k<<<(ngrp + 7) / 8, 256, 0, stream>>>(rowptr, cpack, pe, out, n, L);
    }
}

// Round 15
// 532.763 us; speedup vs baseline: 1.1841x; 1.0624x over previous
//
#include <hip/hip_runtime.h>

#define NN 100000
#define NE 1600000
#define DF 32
#define DEPTH 10
#define LSTRIDE ((DEPTH + 1) * DF) /* 352 floats per node in d_out */
#define SCAN_BLOCKS 256
#define SCAN_T 256
#define PAD 8
#define PADM (~(PAD - 1))

// zero cnt only (0.4MB)
__global__ void zcnt_k(int* __restrict__ cnt, int n4) {
    int i = blockIdx.x * blockDim.x + threadIdx.x;
    if (i < n4) ((int4*)cnt)[i] = make_int4(0, 0, 0, 0);
}

// histogram + per-edge rank within its row (atomic result was free)
__global__ void hist_k(const int* __restrict__ row, int* __restrict__ cnt,
                       int* __restrict__ prank, int e) {
    int i = blockIdx.x * blockDim.x + threadIdx.x;
    int stride = gridDim.x * blockDim.x;
    for (; i < e; i += stride) {
        int r = __builtin_nontemporal_load(&row[i]);
        prank[i] = atomicAdd(&cnt[r], 1);
    }
}

// --- multi-block scan over PADDED counts ((cnt+PAD-1)&PADM) ---
__global__ void scan_partial_k(const int* __restrict__ cnt, int* __restrict__ bsum,
                               int n, int chunk) {
    __shared__ int red[SCAN_T];
    int b = blockIdx.x, t = threadIdx.x;
    int beg = b * chunk, end = min(n, beg + chunk);
    int s = 0;
    for (int i = beg + t; i < end; i += SCAN_T) s += (cnt[i] + PAD - 1) & PADM;
    red[t] = s;
    __syncthreads();
    for (int off = SCAN_T / 2; off; off >>= 1) {
        if (t < off) red[t] += red[t + off];
        __syncthreads();
    }
    if (t == 0) bsum[b] = red[0];
}

__global__ void scan_bsum_k(const int* __restrict__ bsum, int* __restrict__ boff) {
    __shared__ int s[SCAN_BLOCKS];
    int t = threadIdx.x;
    s[t] = bsum[t];
    __syncthreads();
    for (int off = 1; off < SCAN_BLOCKS; off <<= 1) {
        int v = (t >= off) ? s[t - off] : 0;
        __syncthreads();
        s[t] += v;
        __syncthreads();
    }
    boff[t] = (t == 0) ? 0 : s[t - 1];
}

// emit padded-exclusive-prefix rowptr; also compute dinv from real cnt (fused).
__global__ void scan_emit_k(const int* __restrict__ cnt, const int* __restrict__ boff,
                            int* __restrict__ rowptr, float* __restrict__ dinv,
                            int n, int chunk) {
    __shared__ int tile[SCAN_T];
    int b = blockIdx.x, t = threadIdx.x;
    int beg = b * chunk, end = min(n, beg + chunk);
    int run = boff[b];
    for (int base = beg; base < end; base += SCAN_T) {
        int i = base + t;
        int creal = (i < end) ? cnt[i] : 0;
        int c = (creal + PAD - 1) & PADM;
        tile[t] = c;
        __syncthreads();
        for (int off = 1; off < SCAN_T; off <<= 1) {
            int v = (t >= off) ? tile[t - off] : 0;
            __syncthreads();
            tile[t] += v;
            __syncthreads();
        }
        if (i < end) {
            rowptr[i] = run + tile[t] - c; // exclusive prefix of padded counts
            float d = (creal == 0) ? 1.0f : (float)creal;
            dinv[i] = rsqrtf(d);
        }
        run += tile[SCAN_T - 1];
        __syncthreads();
    }
    if (b == gridDim.x - 1 && t == 0) rowptr[n] = run;
}

// zero only the pad slots: [rowptr[r]+cnt[r], rowptr[r+1])
__global__ void pad_k(const int* __restrict__ rowptr, const int* __restrict__ cnt,
                      unsigned long long* __restrict__ cpack, int n) {
    int r = blockIdx.x * blockDim.x + threadIdx.x;
    if (r < n) {
        int p = rowptr[r] + cnt[r];
        int end = rowptr[r + 1];
        for (; p < end; ++p) cpack[p] = 0ull;
    }
}

// atomic-free scatter: pos = rowptr[row] + prank
__global__ void scatter_k(const int* __restrict__ row, const int* __restrict__ col,
                          const float* __restrict__ ea, const float* __restrict__ dinv,
                          const int* __restrict__ rowptr, const int* __restrict__ prank,
                          unsigned long long* __restrict__ cpack, int e) {
    int i = blockIdx.x * blockDim.x + threadIdx.x;
    int stride = gridDim.x * blockDim.x;
    for (; i < e; i += stride) {
        int r = __builtin_nontemporal_load(&row[i]);
        int c = __builtin_nontemporal_load(&col[i]);
        float a = __builtin_nontemporal_load(&ea[i]);
        int pr = __builtin_nontemporal_load(&prank[i]);
        float v = dinv[r] * a * dinv[c];
        int pos = rowptr[r] + pr;
        cpack[pos] = ((unsigned long long)(unsigned)__float_as_int(v) << 32) | (unsigned)c;
    }
}

// out[node][0][:] = x[node][:]  (float4 vectorized)
__global__ void copy_k(const float* __restrict__ x, float* __restrict__ out, int n) {
    int t = blockIdx.x * blockDim.x + threadIdx.x; // n*8 float4s
    if (t < n * 8) {
        int node = t >> 3, q = t & 7;
        ((float4*)out)[(size_t)node * (LSTRIDE / 4) + q] = ((const float4*)x)[t];
    }
}

// one 32-lane group per row; lane = feature; branch-free unroll-8 over pad-8 CSR.
// __launch_bounds__(256, 8): cap VGPR at 64 -> 8 waves/SIMD (32/CU) for max
// outstanding-gather concurrency (R15 single-variable occupancy test).
__global__ __launch_bounds__(256, 8) void spmm_k(const int* __restrict__ rowptr,
                                                 const unsigned long long* __restrict__ cpack,
                                                 const float* __restrict__ pe,
                                                 float* __restrict__ out, int n, int layer) {
    int gid = blockIdx.x * 8 + (threadIdx.x >> 5);
    int lane = threadIdx.x & 31;
    if (gid >= n) return;
    float alpha = tanhf(pe[layer]); // BASE_ALPHA = 1
    const float* __restrict__ hsrc = out + (size_t)layer * DF + lane;
    int beg = rowptr[gid], end = rowptr[gid + 1]; // multiple of 8 apart
    float acc = 0.f;
    for (int base = beg; base < end; base += 8) {
        unsigned long long p[8];
#pragma unroll
        for (int u = 0; u < 8; ++u) p[u] = __builtin_nontemporal_load(&cpack[base + u]);
        float h[8];
#pragma unroll
        for (int u = 0; u < 8; ++u)
            h[u] = hsrc[(unsigned)(p[u] & 0xFFFFFFFFu) * (unsigned)LSTRIDE];
#pragma unroll
        for (int u = 0; u < 8; ++u)
            acc = fmaf(__uint_as_float((unsigned)(p[u] >> 32)), h[u], acc);
    }
    out[(size_t)gid * LSTRIDE + (layer + 1) * DF + lane] = alpha * acc;
}

extern "C" void kernel_launch(void* const* d_in, const int* in_sizes, int n_in,
                              void* d_out, int out_size, void* d_ws, size_t ws_size,
                              hipStream_t stream) {
    const float* x  = (const float*)d_in[0];
    const int*   ei = (const int*)d_in[1];
    const float* ea = (const float*)d_in[2];
    const float* pe = (const float*)d_in[3];
    float* out = (float*)d_out;

    const int n = in_sizes[0] / DF;   // 100000
    const int e = in_sizes[2];        // 1600000
    const int* row = ei;
    const int* col = ei + e;

    // workspace layout
    int*   cnt    = (int*)d_ws;               // n  (16B-aligned: ws base)
    int*   rowptr = cnt + n;                  // n+1
    float* dinv   = (float*)(rowptr + n + 1); // n
    int*   bsum   = (int*)(dinv + n);         // SCAN_BLOCKS
    int*   boff   = bsum + SCAN_BLOCKS;       // SCAN_BLOCKS
    int*   prank  = boff + SCAN_BLOCKS;       // e
    size_t off = ((size_t)(prank + e) - (size_t)d_ws + 15) & ~(size_t)15;
    unsigned long long* cpack = (unsigned long long*)((char*)d_ws + off); // e + (PAD-1)n

    const int n4_cnt = (n + 3) / 4;
    const int chunk = (n + SCAN_BLOCKS - 1) / SCAN_BLOCKS;

    zcnt_k<<<(n4_cnt + 255) / 256, 256, 0, stream>>>(cnt, n4_cnt);
    hist_k<<<2048, 256, 0, stream>>>(row, cnt, prank, e);
    scan_partial_k<<<SCAN_BLOCKS, SCAN_T, 0, stream>>>(cnt, bsum, n, chunk);
    scan_bsum_k<<<1, SCAN_BLOCKS, 0, stream>>>(bsum, boff);
    scan_emit_k<<<SCAN_BLOCKS, SCAN_T, 0, stream>>>(cnt, boff, rowptr, dinv, n, chunk);
    pad_k<<<(n + 255) / 256, 256, 0, stream>>>(rowptr, cnt, cpack, n);
    scatter_k<<<2048, 256, 0, stream>>>(row, col, ea, dinv, rowptr, prank, cpack, e);
    copy_k<<<(n * 8 + 255) / 256, 256, 0, stream>>>(x, out, n);

    for (int L = 0; L < DEPTH; ++L) {
        spmm_k<<<(n + 7) / 8, 256, 0, stream>>>(rowptr, cpack, pe, out, n, L);
    }
}